// Round 2
// baseline (845.368 us; speedup 1.0000x reference)
//
#include <hip/hip_runtime.h>

#define SEQ  720
#define PRED 720
#define RANK 16
#define CTXD 128
#define HID  64
#define BATCH 256
#define ODIM  (RANK * (SEQ + PRED))   // 23040
#define ASIZE (RANK * PRED)           // 11520

#define PT 48                 // p-rows per k_weff block (720/48 = 15 tiles, exact)
#define ST 256                // s-cols per k_weff block (3 tiles, last masked)
#define RPW (PT / 4)          // rows per wave = 12

typedef float v4f __attribute__((ext_vector_type(4)));

#define FMA4(ci, av, bv)                 \
    ci.x = fmaf(av, bv.x, ci.x);         \
    ci.y = fmaf(av, bv.y, ci.y);         \
    ci.z = fmaf(av, bv.z, ci.z);         \
    ci.w = fmaf(av, bv.w, ci.w);

// ---------------------------------------------------------------------------
// K1: hidden[b,k] = relu(ctx[b,:] @ W1[k,:] + b1[k]);  (256, 64)
// ---------------------------------------------------------------------------
__global__ __launch_bounds__(64) void k_hidden(const float* __restrict__ ctx,
                                               const float* __restrict__ W1,
                                               const float* __restrict__ b1,
                                               float* __restrict__ hid)
{
    __shared__ alignas(16) float cl[CTXD];
    int b = blockIdx.x, k = threadIdx.x;
    cl[k]      = ctx[b * CTXD + k];
    cl[k + 64] = ctx[b * CTXD + k + 64];
    __syncthreads();
    float acc = b1[k];
    const float* wr = W1 + k * CTXD;
#pragma unroll
    for (int c = 0; c < CTXD; c += 4) {
        float4 w  = *(const float4*)(wr + c);
        float4 xv = *(const float4*)(cl + c);
        acc = fmaf(w.x, xv.x, acc);
        acc = fmaf(w.y, xv.y, acc);
        acc = fmaf(w.z, xv.z, acc);
        acc = fmaf(w.w, xv.w, acc);
    }
    hid[b * HID + k] = fmaxf(acc, 0.0f);
}

// ---------------------------------------------------------------------------
// K2: h[b,o] = hidden[b,:] @ W2[o,:] + b2[o];  (256, 23040)
// grid (ODIM/64, BATCH/64), 256 threads, 64x64 tile, 4x4 per thread.
// ---------------------------------------------------------------------------
__global__ __launch_bounds__(256) void k_hyper(const float* __restrict__ hid,
                                               const float* __restrict__ W2,
                                               const float* __restrict__ b2,
                                               float* __restrict__ h)
{
    int ot = blockIdx.x, bt = blockIdx.y;
    __shared__ alignas(16) float Hl[64 * 68];   // [b_local][k], pad 68 -> 2-way (free)
    __shared__ alignas(16) float Wl[64 * 68];   // [o_local][k]
    int tid = threadIdx.x;

    const float* hg = hid + (size_t)bt * 64 * HID;   // contiguous 4096 floats
    const float* wg = W2  + (size_t)ot * 64 * HID;   // contiguous 4096 floats
#pragma unroll
    for (int n = 0; n < 4; n++) {
        int g = tid * 4 + n * 1024;
        float4 hv = *(const float4*)(hg + g);
        float4 wv = *(const float4*)(wg + g);
        int row = g >> 6, colk = g & 63;
        *(float4*)&Hl[row * 68 + colk] = hv;
        *(float4*)&Wl[row * 68 + colk] = wv;
    }
    __syncthreads();

    int tx = tid & 15, ty = tid >> 4;
    float c[4][4];
#pragma unroll
    for (int j = 0; j < 4; j++) {
        float bv = b2[ot * 64 + j * 16 + tx];
        c[0][j] = bv; c[1][j] = bv; c[2][j] = bv; c[3][j] = bv;
    }
#pragma unroll
    for (int kc = 0; kc < HID; kc += 4) {
        float4 hv[4], wv[4];
#pragma unroll
        for (int i = 0; i < 4; i++) hv[i] = *(const float4*)&Hl[(ty * 4 + i) * 68 + kc];
#pragma unroll
        for (int j = 0; j < 4; j++) wv[j] = *(const float4*)&Wl[(j * 16 + tx) * 68 + kc];
#pragma unroll
        for (int i = 0; i < 4; i++)
#pragma unroll
            for (int j = 0; j < 4; j++) {
                c[i][j] = fmaf(hv[i].x, wv[j].x, c[i][j]);
                c[i][j] = fmaf(hv[i].y, wv[j].y, c[i][j]);
                c[i][j] = fmaf(hv[i].z, wv[j].z, c[i][j]);
                c[i][j] = fmaf(hv[i].w, wv[j].w, c[i][j]);
            }
    }
#pragma unroll
    for (int i = 0; i < 4; i++) {
        int b = bt * 64 + ty * 4 + i;
        float* hb = h + (size_t)b * ODIM + ot * 64;
#pragma unroll
        for (int j = 0; j < 4; j++)
            hb[j * 16 + tx] = c[i][j];
    }
}

// ---------------------------------------------------------------------------
// K3: W_eff[b,p,s] = W[p,s] + sum_r A[b,p,r]*B[b,r,s]; y[b,p] += W_eff*x
// grid (3 s-tiles x 15 p-tiles x 256 batches), 256 threads.
// Tile: 48 p-rows x 256 s-cols. Each wave owns 12 whole rows -> every
// nontemporal wave-store is 1 KB contiguous. y reduced per row via 6
// shfl_xor steps (no LDS round-trip, no second barrier), 1 atomic/row.
// A[b,p,r] = h[b, p*16+r];  B[b,r,s] = h[b, 11520 + r*720 + s]
// ---------------------------------------------------------------------------
__global__ __launch_bounds__(256) void k_weff(const float* __restrict__ h,
                                              const float* __restrict__ W,
                                              const float* __restrict__ x,
                                              float* __restrict__ y,
                                              float* __restrict__ weff)
{
    const int st = blockIdx.x, pt = blockIdx.y, b = blockIdx.z;
    const int s0 = st * ST, p0 = pt * PT;
    __shared__ alignas(16) float Al[PT * RANK];   // 768 floats  (3 KB), flat h slice
    __shared__ alignas(16) float Bl[RANK][ST];    // 4096 floats (16 KB)
    const int tid = threadIdx.x;
    const float* hb = h + (size_t)b * ODIM;

    // A tile: 48 rows x 16 ranks = 768 contiguous floats in h
    if (tid < (PT * RANK / 4))   // 192 threads, one float4 each
        *(float4*)&Al[tid * 4] = *(const float4*)(hb + p0 * RANK + tid * 4);

    // B tile: 16 r-rows x 256 s, zero-filled past SEQ so rank loop is unmasked
    {
        const int r = tid >> 4, c4 = tid & 15;
        const float* brow = hb + ASIZE + r * SEQ;
#pragma unroll
        for (int q = 0; q < 4; q++) {
            int col = q * 64 + c4 * 4;
            float4 v = make_float4(0.f, 0.f, 0.f, 0.f);
            if (s0 + col < SEQ) v = *(const float4*)(brow + s0 + col);
            *(float4*)&Bl[r][col] = v;
        }
    }
    __syncthreads();

    const int wave = tid >> 6, lane = tid & 63;
    const int s = s0 + lane * 4;
    const bool sv = (s < SEQ);
    const int pbase = p0 + wave * RPW;   // this wave's 12 contiguous rows

    float4 c[RPW];
#pragma unroll
    for (int k = 0; k < RPW; k++) c[k] = make_float4(0.f, 0.f, 0.f, 0.f);

#pragma unroll
    for (int rc = 0; rc < RANK; rc += 4) {
        float4 bb[4];
#pragma unroll
        for (int j = 0; j < 4; j++) bb[j] = *(const float4*)&Bl[rc + j][lane * 4];
#pragma unroll
        for (int k = 0; k < RPW; k++) {
            // same address across the wave -> LDS broadcast, conflict-free
            float4 a = *(const float4*)&Al[(wave * RPW + k) * RANK + rc];
            FMA4(c[k], a.x, bb[0]);
            FMA4(c[k], a.y, bb[1]);
            FMA4(c[k], a.z, bb[2]);
            FMA4(c[k], a.w, bb[3]);
        }
    }

    float4 xv = make_float4(0.f, 0.f, 0.f, 0.f);
    if (sv) xv = *(const float4*)(x + (size_t)b * SEQ + s);

    float* wb = weff + (size_t)b * ((size_t)PRED * SEQ);
#pragma unroll
    for (int k = 0; k < RPW; k++) {
        const int p = pbase + k;
        float part = 0.0f;
        if (sv) {
            float4 wv = *(const float4*)(W + (size_t)p * SEQ + s);
            v4f e;
            e.x = wv.x + c[k].x;
            e.y = wv.y + c[k].y;
            e.z = wv.z + c[k].z;
            e.w = wv.w + c[k].w;
            __builtin_nontemporal_store(e, (v4f*)(wb + (size_t)p * SEQ + s));
            part = e.x * xv.x + e.y * xv.y + e.z * xv.z + e.w * xv.w;
        }
        // 64-lane butterfly reduction for y[b,p]
#pragma unroll
        for (int m = 32; m > 0; m >>= 1)
            part += __shfl_xor(part, m, 64);
        if (lane == 0) atomicAdd(y + (size_t)b * PRED + p, part);
    }
}

// ---------------------------------------------------------------------------
extern "C" void kernel_launch(void* const* d_in, const int* in_sizes, int n_in,
                              void* d_out, int out_size, void* d_ws, size_t ws_size,
                              hipStream_t stream)
{
    const float* x   = (const float*)d_in[0];
    const float* ctx = (const float*)d_in[1];
    const float* W   = (const float*)d_in[2];
    const float* W1  = (const float*)d_in[3];
    const float* b1  = (const float*)d_in[4];
    const float* W2  = (const float*)d_in[5];
    const float* b2  = (const float*)d_in[6];

    float* out  = (float*)d_out;
    float* yout = out;                                  // (256, 720, 1)
    float* weff = out + (size_t)BATCH * PRED;           // (256, 720, 720)

    float* hid = (float*)d_ws;                          // 256*64 floats
    float* h   = hid + (size_t)BATCH * HID;             // 256*23040 floats

    // zero y region (k_weff accumulates y via atomics, 3 partials per element)
    (void)hipMemsetAsync(yout, 0, (size_t)BATCH * PRED * sizeof(float), stream);

    k_hidden<<<dim3(BATCH), dim3(64), 0, stream>>>(ctx, W1, b1, hid);
    k_hyper<<<dim3(ODIM / 64, BATCH / 64), dim3(256), 0, stream>>>(hid, W2, b2, h);
    k_weff<<<dim3(SEQ / ST + 1, PRED / PT, BATCH), dim3(256), 0, stream>>>(h, W, x, yout, weff);
}

// Round 3
// 646.004 us; speedup vs baseline: 1.3086x; 1.3086x over previous
//
#include <hip/hip_runtime.h>

#define SEQ  720
#define PRED 720
#define RANK 16
#define CTXD 128
#define HID  64
#define BATCH 256
#define ODIM  (RANK * (SEQ + PRED))   // 23040
#define ASIZE (RANK * PRED)           // 11520

#define PT 16                  // p-rows per k_weff block (45 tiles, exact)
#define ST 256                 // s-cols per k_weff block (3 tiles, last masked)

typedef float v4f __attribute__((ext_vector_type(4)));

#define FMA4(ci, av, bv)                 \
    ci.x = fmaf(av, bv.x, ci.x);         \
    ci.y = fmaf(av, bv.y, ci.y);         \
    ci.z = fmaf(av, bv.z, ci.z);         \
    ci.w = fmaf(av, bv.w, ci.w);

// ---------------------------------------------------------------------------
// K1: hidden[b,k] = relu(ctx[b,:] @ W1[k,:] + b1[k]);  (256, 64)
// ---------------------------------------------------------------------------
__global__ __launch_bounds__(64) void k_hidden(const float* __restrict__ ctx,
                                               const float* __restrict__ W1,
                                               const float* __restrict__ b1,
                                               float* __restrict__ hid)
{
    __shared__ alignas(16) float cl[CTXD];
    int b = blockIdx.x, k = threadIdx.x;
    cl[k]      = ctx[b * CTXD + k];
    cl[k + 64] = ctx[b * CTXD + k + 64];
    __syncthreads();
    float acc = b1[k];
    const float* wr = W1 + k * CTXD;
#pragma unroll
    for (int c = 0; c < CTXD; c += 4) {
        float4 w  = *(const float4*)(wr + c);
        float4 xv = *(const float4*)(cl + c);
        acc = fmaf(w.x, xv.x, acc);
        acc = fmaf(w.y, xv.y, acc);
        acc = fmaf(w.z, xv.z, acc);
        acc = fmaf(w.w, xv.w, acc);
    }
    hid[b * HID + k] = fmaxf(acc, 0.0f);
}

// ---------------------------------------------------------------------------
// K2: h[b,o] = hidden[b,:] @ W2[o,:] + b2[o];  (256, 23040)
// grid (ODIM/64, BATCH/64), 256 threads, 64x64 tile, 4x4 per thread.
// ---------------------------------------------------------------------------
__global__ __launch_bounds__(256) void k_hyper(const float* __restrict__ hid,
                                               const float* __restrict__ W2,
                                               const float* __restrict__ b2,
                                               float* __restrict__ h)
{
    int ot = blockIdx.x, bt = blockIdx.y;
    __shared__ alignas(16) float Hl[64 * 68];   // [b_local][k], pad 68 -> 2-way (free)
    __shared__ alignas(16) float Wl[64 * 68];   // [o_local][k]
    int tid = threadIdx.x;

    const float* hg = hid + (size_t)bt * 64 * HID;   // contiguous 4096 floats
    const float* wg = W2  + (size_t)ot * 64 * HID;   // contiguous 4096 floats
#pragma unroll
    for (int n = 0; n < 4; n++) {
        int g = tid * 4 + n * 1024;
        float4 hv = *(const float4*)(hg + g);
        float4 wv = *(const float4*)(wg + g);
        int row = g >> 6, colk = g & 63;
        *(float4*)&Hl[row * 68 + colk] = hv;
        *(float4*)&Wl[row * 68 + colk] = wv;
    }
    __syncthreads();

    int tx = tid & 15, ty = tid >> 4;
    float c[4][4];
#pragma unroll
    for (int j = 0; j < 4; j++) {
        float bv = b2[ot * 64 + j * 16 + tx];
        c[0][j] = bv; c[1][j] = bv; c[2][j] = bv; c[3][j] = bv;
    }
#pragma unroll
    for (int kc = 0; kc < HID; kc += 4) {
        float4 hv[4], wv[4];
#pragma unroll
        for (int i = 0; i < 4; i++) hv[i] = *(const float4*)&Hl[(ty * 4 + i) * 68 + kc];
#pragma unroll
        for (int j = 0; j < 4; j++) wv[j] = *(const float4*)&Wl[(j * 16 + tx) * 68 + kc];
#pragma unroll
        for (int i = 0; i < 4; i++)
#pragma unroll
            for (int j = 0; j < 4; j++) {
                c[i][j] = fmaf(hv[i].x, wv[j].x, c[i][j]);
                c[i][j] = fmaf(hv[i].y, wv[j].y, c[i][j]);
                c[i][j] = fmaf(hv[i].z, wv[j].z, c[i][j]);
                c[i][j] = fmaf(hv[i].w, wv[j].w, c[i][j]);
            }
    }
#pragma unroll
    for (int i = 0; i < 4; i++) {
        int b = bt * 64 + ty * 4 + i;
        float* hb = h + (size_t)b * ODIM + ot * 64;
#pragma unroll
        for (int j = 0; j < 4; j++)
            hb[j * 16 + tx] = c[i][j];
    }
}

// ---------------------------------------------------------------------------
// K_Y: y[b,p] = dot(W[p,:], x[b,:]) + dot(A[b,p,:], Bx[b,:])
//      where Bx[b,r] = dot(B[b,r,:], x[b,:])
// Algebraically identical to einsum(W_eff, x); avoids touching W_eff.
// One block per batch. W is 2 MB -> L2-resident broadcast read.
// ---------------------------------------------------------------------------
__global__ __launch_bounds__(256) void k_y(const float* __restrict__ h,
                                           const float* __restrict__ W,
                                           const float* __restrict__ x,
                                           float* __restrict__ y)
{
    const int b = blockIdx.x, tid = threadIdx.x;
    __shared__ alignas(16) float xs[SEQ];     // 720
    __shared__ float red[256];
    __shared__ float bxs[RANK];
    const float* hb = h + (size_t)b * ODIM;

    if (tid < SEQ / 4)
        *(float4*)&xs[tid * 4] = *(const float4*)(x + (size_t)b * SEQ + tid * 4);
    __syncthreads();

    // Bx[r] = sum_s B[b,r,s]*x[b,s]; 16 r-rows x 16 col-chunks of 45
    {
        const int r = tid >> 4, c = tid & 15;
        const float* brow = hb + ASIZE + r * SEQ + c * 45;
        float part = 0.0f;
#pragma unroll
        for (int i = 0; i < 45; i++) part = fmaf(brow[i], xs[c * 45 + i], part);
        red[tid] = part;
    }
    __syncthreads();
    if (tid < RANK) {
        float s = 0.0f;
#pragma unroll
        for (int j = 0; j < 16; j++) s += red[tid * 16 + j];
        bxs[tid] = s;
    }
    __syncthreads();

    for (int p = tid; p < PRED; p += 256) {
        const float* wr = W + (size_t)p * SEQ;
        float acc = 0.0f;
#pragma unroll 4
        for (int c4 = 0; c4 < SEQ; c4 += 4) {
            float4 wv = *(const float4*)(wr + c4);
            acc = fmaf(wv.x, xs[c4],     acc);
            acc = fmaf(wv.y, xs[c4 + 1], acc);
            acc = fmaf(wv.z, xs[c4 + 2], acc);
            acc = fmaf(wv.w, xs[c4 + 3], acc);
        }
        const float* ar = hb + p * RANK;
#pragma unroll
        for (int r = 0; r < RANK; r++) acc = fmaf(ar[r], bxs[r], acc);
        y[(size_t)b * PRED + p] = acc;
    }
}

// ---------------------------------------------------------------------------
// K3: W_eff[b,p,s] = W[p,s] + sum_r A[b,p,r]*B[b,r,s]  — pure store stream.
// grid (3 s-tiles x 45 p-tiles x 256 batches), 256 threads, tile 16p x 256s.
// Each wave owns 4 whole rows: 4 contiguous 1 KB nontemporal wave-stores,
// issued back-to-back with no dependent work between them (no y, no shfl,
// no atomics). Slim register footprint for occupancy.
// A[b,p,r] = h[b, p*16+r];  B[b,r,s] = h[b, 11520 + r*720 + s]
// ---------------------------------------------------------------------------
__global__ __launch_bounds__(256, 4) void k_weff(const float* __restrict__ h,
                                                 const float* __restrict__ W,
                                                 float* __restrict__ weff)
{
    const int st = blockIdx.x, pt = blockIdx.y, b = blockIdx.z;
    const int s0 = st * ST, p0 = pt * PT;
    __shared__ alignas(16) float Al[PT * RANK];   // 256 floats (1 KB)
    __shared__ alignas(16) float Bl[RANK][ST];    // 4096 floats (16 KB)
    const int tid = threadIdx.x;
    const float* hb = h + (size_t)b * ODIM;

    // A tile: 16 rows x 16 ranks = 256 contiguous floats in h
    if (tid < (PT * RANK / 4))   // 64 threads, one float4 each
        *(float4*)&Al[tid * 4] = *(const float4*)(hb + p0 * RANK + tid * 4);

    // B tile: 16 r-rows x 256 s, zero-filled past SEQ so rank loop is unmasked
    {
        const int r = tid >> 4, c4 = tid & 15;
        const float* brow = hb + ASIZE + r * SEQ;
#pragma unroll
        for (int q = 0; q < 4; q++) {
            int col = q * 64 + c4 * 4;
            float4 v = make_float4(0.f, 0.f, 0.f, 0.f);
            if (s0 + col < SEQ) v = *(const float4*)(brow + s0 + col);
            *(float4*)&Bl[r][col] = v;
        }
    }
    __syncthreads();

    const int wave = tid >> 6, lane = tid & 63;
    const int s = s0 + lane * 4;
    const bool sv = (s < SEQ);
    const int pbase = p0 + wave * 4;    // this wave's 4 contiguous rows

    float4 c[4];
#pragma unroll
    for (int k = 0; k < 4; k++) c[k] = make_float4(0.f, 0.f, 0.f, 0.f);

#pragma unroll
    for (int rc = 0; rc < RANK; rc += 4) {
        float4 bb[4];
#pragma unroll
        for (int j = 0; j < 4; j++) bb[j] = *(const float4*)&Bl[rc + j][lane * 4];
#pragma unroll
        for (int k = 0; k < 4; k++) {
            // same address across the wave -> LDS broadcast, conflict-free
            float4 a = *(const float4*)&Al[(wave * 4 + k) * RANK + rc];
            FMA4(c[k], a.x, bb[0]);
            FMA4(c[k], a.y, bb[1]);
            FMA4(c[k], a.z, bb[2]);
            FMA4(c[k], a.w, bb[3]);
        }
    }

    if (sv) {
        float* wb = weff + (size_t)b * ((size_t)PRED * SEQ) + s;
        v4f e[4];
#pragma unroll
        for (int k = 0; k < 4; k++) {
            float4 wv = *(const float4*)(W + (size_t)(pbase + k) * SEQ + s);
            e[k].x = wv.x + c[k].x;
            e[k].y = wv.y + c[k].y;
            e[k].z = wv.z + c[k].z;
            e[k].w = wv.w + c[k].w;
        }
#pragma unroll
        for (int k = 0; k < 4; k++)
            __builtin_nontemporal_store(e[k], (v4f*)(wb + (size_t)(pbase + k) * SEQ));
    }
}

// ---------------------------------------------------------------------------
extern "C" void kernel_launch(void* const* d_in, const int* in_sizes, int n_in,
                              void* d_out, int out_size, void* d_ws, size_t ws_size,
                              hipStream_t stream)
{
    const float* x   = (const float*)d_in[0];
    const float* ctx = (const float*)d_in[1];
    const float* W   = (const float*)d_in[2];
    const float* W1  = (const float*)d_in[3];
    const float* b1  = (const float*)d_in[4];
    const float* W2  = (const float*)d_in[5];
    const float* b2  = (const float*)d_in[6];

    float* out  = (float*)d_out;
    float* yout = out;                                  // (256, 720, 1)
    float* weff = out + (size_t)BATCH * PRED;           // (256, 720, 720)

    float* hid = (float*)d_ws;                          // 256*64 floats
    float* h   = hid + (size_t)BATCH * HID;             // 256*23040 floats

    k_hidden<<<dim3(BATCH), dim3(64), 0, stream>>>(ctx, W1, b1, hid);
    k_hyper<<<dim3(ODIM / 64, BATCH / 64), dim3(256), 0, stream>>>(hid, W2, b2, h);
    k_y<<<dim3(BATCH), dim3(256), 0, stream>>>(h, W, x, yout);
    k_weff<<<dim3(SEQ / ST + 1, PRED / PT, BATCH), dim3(256), 0, stream>>>(h, W, weff);
}